// Round 6
// baseline (97.102 us; speedup 1.0000x reference)
//
#include <hip/hip_runtime.h>

// BSpline evaluation, MI355X.
// t [2048] f32 sorted, c [512,2048] f32, delta [1] i32.
// out = sample_points [S] ++ spline_values [S, DIM]; S=32768, DIM=512.
// B rows have <=4 nonzeros (cols j-3..j, j = knot span), incl. the reference's
// stale-column quirk (col i final degree = min(3, NK-1-i)).
// R6: weights fused into eval (per-lane triangle for sample s0+(lane&7),
// __shfl broadcast) -> 2 dispatches total, no jbuf/bbuf round-trip.
// Eval wave = 8 samples x full row, hierarchical span-uniform fallback,
// NT stores. Eval is store-bound (~67 MB compulsory writes).

#define DEG 3

typedef float vfloat4 __attribute__((ext_vector_type(4)));

__device__ __forceinline__ float kn(const float* __restrict__ t, int i) {
    return (i < DEG + 1) ? 0.0f : t[i - (DEG + 1)];
}

// ---------------- prep: transpose c [DIM][NK] -> cT [NK][DIM] ----------------
#define TILE 32
__global__ __launch_bounds__(256) void transpose_kernel(
    const float* __restrict__ c, float* __restrict__ cT, int NK, int DIM)
{
    __shared__ float tile[TILE][TILE + 1];
    int bx = blockIdx.x % (NK / TILE);
    int by = blockIdx.x / (NK / TILE);
    int tx = threadIdx.x % TILE;
    int ty = threadIdx.x / TILE;         // 0..7
    int x = bx * TILE + tx;
    int y = by * TILE + ty;
    #pragma unroll
    for (int i = 0; i < TILE; i += 8)
        tile[ty + i][tx] = c[(size_t)(y + i) * NK + x];
    __syncthreads();
    int x2 = by * TILE + tx;
    int y2 = bx * TILE + ty;
    #pragma unroll
    for (int i = 0; i < TILE; i += 8)
        cT[(size_t)(y2 + i) * DIM + x2] = tile[tx][ty + i];
}

// ---------------- fused eval: one wave = 8 consecutive samples x full row ---
__device__ __forceinline__ vfloat4 dot4(const vfloat4 b, const vfloat4 a0,
                                        const vfloat4 a1, const vfloat4 a2,
                                        const vfloat4 a3) {
    return b.x * a0 + b.y * a1 + b.z * a2 + b.w * a3;
}

__global__ __launch_bounds__(256) void bspline_eval(
    const float* __restrict__ t, const int* __restrict__ delta_p,
    const float* __restrict__ cT, float* __restrict__ out_pts,
    vfloat4* __restrict__ out_spline, int NK, int DIM)
{
    const int nvec = DIM >> 2;                       // 128
    int gtid = blockIdx.x * blockDim.x + threadIdx.x;
    int wid  = gtid >> 6;
    int lane = gtid & 63;
    int s0   = __builtin_amdgcn_readfirstlane(wid << 3);

    // ---- inline weights: every lane computes sample s0 + (lane&7) ----
    const int m_my = lane & 7;
    const int s_my = s0 + m_my;
    const float delta = (float)(*delta_p);
    const float sv = (float)s_my * delta;
    if (lane < 8) out_pts[s_my] = sv;

    // rightmost jj in [DEG, NK+DEG-1] with kn(jj) <= sv
    int lo = DEG, hi = NK + DEG - 1;
    while (lo < hi) {
        int mid = (lo + hi + 1) >> 1;
        if (kn(t, mid) <= sv) lo = mid; else hi = mid - 1;
    }
    int jj = lo;
    float bw[DEG + 1];

    if (jj >= NK) {  // beyond last degree-0 span: zero row
        jj = NK - 1;
        bw[0] = bw[1] = bw[2] = bw[3] = 0.0f;
    } else {
        // Cox-de Boor triangle: N[d][k] = val(jj-d+k, d), where(denom==0 -> 0)
        float N[DEG + 1][DEG + 1];
        N[0][0] = 1.0f;
        #pragma unroll
        for (int d = 1; d <= DEG; ++d) {
            #pragma unroll
            for (int k = 0; k <= d; ++k) {
                int i = jj - d + k;
                float vpi  = (k >= 1) ? N[d - 1][k - 1] : 0.0f;
                float vpi1 = (k <= d - 1) ? N[d - 1][k] : 0.0f;
                float ki   = kn(t, i);
                float kid  = kn(t, i + d);
                float ki1  = kn(t, i + 1);
                float kid1 = kn(t, i + d + 1);
                float den1 = kid - ki;
                float den2 = kid1 - ki1;
                float w1 = (den1 != 0.0f) ? (sv - ki) / den1 : 0.0f;
                float w2 = (den2 != 0.0f) ? (kid1 - sv) / den2 : 0.0f;
                N[d][k] = w1 * vpi + w2 * vpi1;
            }
        }
        // stale-column quirk: col i keeps degree min(DEG, NK-1-i)
        #pragma unroll
        for (int m = 0; m <= DEG; ++m) {
            int col = jj - DEG + m;
            int deg = NK - 1 - col; if (deg > DEG) deg = DEG;
            int idx = m - DEG + deg;
            bw[m] = (idx >= 0) ? N[deg][idx] : 0.0f;
        }
    }

    // ---- broadcast j/b for the wave's 8 samples (lane m holds sample m) ----
    int j[8];
    vfloat4 b[8];
    #pragma unroll
    for (int m = 0; m < 8; ++m) {
        j[m] = __shfl(jj, m);
        b[m] = (vfloat4){__shfl(bw[0], m), __shfl(bw[1], m),
                         __shfl(bw[2], m), __shfl(bw[3], m)};
    }

    vfloat4* orow = out_spline + (size_t)s0 * nvec + lane;

    if (j[0] == j[7]) {
        const vfloat4* r = (const vfloat4*)(cT + (size_t)(j[0] - 3) * DIM) + lane;
        vfloat4 a0 = r[0],        a0b = r[64];
        vfloat4 a1 = r[nvec],     a1b = r[nvec + 64];
        vfloat4 a2 = r[2 * nvec], a2b = r[2 * nvec + 64];
        vfloat4 a3 = r[3 * nvec], a3b = r[3 * nvec + 64];
        #pragma unroll
        for (int m = 0; m < 8; ++m) {
            __builtin_nontemporal_store(dot4(b[m], a0,  a1,  a2,  a3 ), orow + m * nvec);
            __builtin_nontemporal_store(dot4(b[m], a0b, a1b, a2b, a3b), orow + m * nvec + 64);
        }
    } else {
        #pragma unroll
        for (int h = 0; h < 2; ++h) {
            const int m0 = h * 4;
            if (j[m0] == j[m0 + 3]) {
                const vfloat4* r = (const vfloat4*)(cT + (size_t)(j[m0] - 3) * DIM) + lane;
                vfloat4 a0 = r[0],        a0b = r[64];
                vfloat4 a1 = r[nvec],     a1b = r[nvec + 64];
                vfloat4 a2 = r[2 * nvec], a2b = r[2 * nvec + 64];
                vfloat4 a3 = r[3 * nvec], a3b = r[3 * nvec + 64];
                #pragma unroll
                for (int m = m0; m < m0 + 4; ++m) {
                    __builtin_nontemporal_store(dot4(b[m], a0,  a1,  a2,  a3 ), orow + m * nvec);
                    __builtin_nontemporal_store(dot4(b[m], a0b, a1b, a2b, a3b), orow + m * nvec + 64);
                }
            } else {
                #pragma unroll
                for (int m = m0; m < m0 + 4; ++m) {
                    const vfloat4* r = (const vfloat4*)(cT + (size_t)(j[m] - 3) * DIM) + lane;
                    vfloat4 a0 = r[0],        a0b = r[64];
                    vfloat4 a1 = r[nvec],     a1b = r[nvec + 64];
                    vfloat4 a2 = r[2 * nvec], a2b = r[2 * nvec + 64];
                    vfloat4 a3 = r[3 * nvec], a3b = r[3 * nvec + 64];
                    __builtin_nontemporal_store(dot4(b[m], a0,  a1,  a2,  a3 ), orow + m * nvec);
                    __builtin_nontemporal_store(dot4(b[m], a0b, a1b, a2b, a3b), orow + m * nvec + 64);
                }
            }
        }
    }
}

extern "C" void kernel_launch(void* const* d_in, const int* in_sizes, int n_in,
                              void* d_out, int out_size, void* d_ws, size_t ws_size,
                              hipStream_t stream) {
    const float* t = (const float*)d_in[0];
    const float* c = (const float*)d_in[1];
    const int* delta = (const int*)d_in[2];
    const int NK = in_sizes[0];                 // 2048
    const int DIM = in_sizes[1] / NK;           // 512
    const int S = out_size / (1 + DIM);         // 32768

    float* cT = (float*)d_ws;                   // NK*DIM f32 = 4 MB

    const int TB = (NK / TILE) * (DIM / TILE);  // 1024 blocks
    transpose_kernel<<<TB, 256, 0, stream>>>(c, cT, NK, DIM);

    // one wave per 8-sample group
    int total_threads = (S >> 3) * 64;          // 262144
    bspline_eval<<<total_threads / 256, 256, 0, stream>>>(
        t, delta, cT, (float*)d_out,
        (vfloat4*)((float*)d_out + S), NK, DIM);
}